// Round 16
// baseline (536.809 us; speedup 1.0000x reference)
//
#include <hip/hip_runtime.h>
#include <hip/hip_cooperative_groups.h>

namespace cg = cooperative_groups;

#define N 10
#define D 1024
#define NREL 200
#define KCH 32            // k-slices in the gather (each KLEN rows)
#define KLEN 32           // D / KCH
#define MAXG 8            // max edges per gather group
#define NTHR 256

typedef float f32x4 __attribute__((ext_vector_type(4)));

// ---------------- workspace layout (float offsets) ----------------
// zeroed by build_zero blocks 1..41: [q | k | root | x2acc | aggrel]
#define OFF_Q       0                      // N*D
#define OFF_K       (OFF_Q + N*D)          // N*D
#define OFF_ROOT    (OFF_K + N*D)          // N*D
#define OFF_X2ACC   (OFF_ROOT + N*D)       // N*D
#define OFF_AGGREL  (OFF_X2ACC + N*D)      // D
#define ZERO_FLOATS (OFF_AGGREL + D)       // 41984 = 41 * 1024
#define OFF_EM      ZERO_FLOATS            // N*N*D (fully written each call)
#define OFF_WE      (OFF_EM + N*N*D)       // 128 (fallback path)
#define OFF_LOGITS  (OFF_WE + 128)         // 128 (coop path)
#define OFF_NITEMS  (OFF_LOGITS + 128)     // 16
#define OFF_ITEMS   (OFF_NITEMS + 16)      // 1024 (100 items x 10 ints)
#define OFF_EMPART  (OFF_ITEMS + 1024)     // KCH*N*N*D (13.1 MB, fully written)

// ---- D1: block 0 builds etype groups; blocks 1..41 zero the accumulators ----
__global__ void build_zero(const int* __restrict__ speaker, int* __restrict__ n_items,
                           int* __restrict__ items, float* __restrict__ wsz) {
    if (blockIdx.x > 0) {
        int base = (blockIdx.x - 1) * 1024 + threadIdx.x * 4;
        f32x4 z = 0.f;
        *reinterpret_cast<f32x4*>(wsz + base) = z;
        return;
    }
    __shared__ int sp[N];
    __shared__ int gcnt[NREL];
    __shared__ int ibase[NREL];
    int tid = threadIdx.x;
    if (tid < N) sp[tid] = speaker[tid];
    __syncthreads();
    if (tid < NREL) {
        int c = 0;
        for (int e = 0; e < N * N; ++e) {
            int src = e / N, dst = e % N;
            int et = 2 * (sp[src] * N + sp[dst]) + (src >= dst ? 1 : 0);
            c += (et == tid);
        }
        gcnt[tid] = c;
    }
    __syncthreads();
    if (tid == 0) {
        int b = 0;
        for (int t = 0; t < NREL; ++t) { ibase[t] = b; b += (gcnt[t] + MAXG - 1) / MAXG; }
        *n_items = b;
    }
    __syncthreads();
    if (tid < NREL && gcnt[tid] > 0) {
        int it = ibase[tid], slot = 0;
        int* rec = items + it * 10;
        for (int e = 0; e < N * N; ++e) {
            int src = e / N, dst = e % N;
            int et = 2 * (sp[src] * N + sp[dst]) + (src >= dst ? 1 : 0);
            if (et != tid) continue;
            if (slot == 0) rec[0] = tid;
            rec[2 + slot] = e;
            if (++slot == MAXG) { rec[1] = MAXG; ++it; rec = items + it * 10; slot = 0; }
        }
        if (slot > 0) { rec[1] = slot; for (int g = slot; g < MAXG; ++g) rec[2 + g] = -1; }
    }
}

// ---- D2 (normal dispatch, full occupancy): [bx<100] etype-grouped weight-gather
//      -> em_part; [bx>=100] q/k/root pre-matvecs. R12-exact. ----
__global__ void big_fused(const float* __restrict__ X, const float* __restrict__ Wrel,
                          const int* __restrict__ n_items, const int* __restrict__ items,
                          const float* __restrict__ Wq, const float* __restrict__ Wk,
                          const float* __restrict__ Wroot,
                          float* __restrict__ q, float* __restrict__ kout,
                          float* __restrict__ rootacc, float* __restrict__ em_part) {
    int bx = blockIdx.x, by = blockIdx.y, tid = threadIdx.x;
    if (bx < 100) {
        if (bx >= *n_items) return;
        __shared__ int   meta[10];
        __shared__ float xs[MAXG][KLEN];
        if (tid < 10) meta[tid] = items[bx * 10 + tid];
        __syncthreads();
        int t = meta[0], gsize = meta[1];
        {
            int g = tid >> 5, k = tid & 31;
            int e = meta[2 + g];
            xs[g][k] = (g < gsize) ? X[(e / N) * D + by * KLEN + k] : 0.f;
        }
        __syncthreads();
        int c0 = tid * 4;
        const float* W = Wrel + (size_t)t * D * D + (size_t)by * KLEN * D;
        f32x4 acc[MAXG];
#pragma unroll
        for (int g = 0; g < MAXG; ++g) acc[g] = 0.f;
#pragma unroll 4
        for (int k = 0; k < KLEN; ++k) {
            f32x4 w4 = *reinterpret_cast<const f32x4*>(W + (size_t)k * D + c0);
#pragma unroll
            for (int g = 0; g < MAXG; ++g) acc[g] += xs[g][k] * w4;
        }
        for (int g = 0; g < gsize; ++g) {
            *reinterpret_cast<f32x4*>(
                em_part + ((size_t)(by * (N * N) + meta[2 + g])) * D + c0) = acc[g];
        }
    } else {
        int sel = bx - 100;
        int kb  = (by & 7) * 128;
        int c   = (by >> 3) * 256 + tid;
        const float* W = (sel == 0) ? Wq : (sel == 1) ? Wk : Wroot;
        float*       Y = (sel == 0) ? q  : (sel == 1) ? kout : rootacc;
        __shared__ float xs2[N][128];
        for (int idx = tid; idx < N * 128; idx += 256) {
            int r = idx >> 7, k = idx & 127;
            xs2[r][k] = X[r * D + kb + k];
        }
        __syncthreads();
        float acc[N];
#pragma unroll
        for (int r = 0; r < N; ++r) acc[r] = 0.f;
#pragma unroll 4
        for (int k = 0; k < 128; ++k) {
            float w = W[(size_t)(kb + k) * D + c];
#pragma unroll
            for (int r = 0; r < N; ++r) acc[r] += xs2[r][k] * w;
        }
#pragma unroll
        for (int r = 0; r < N; ++r) atomicAdd(&Y[r * D + c], acc[r]);
    }
}

// phase-overlaid shared memory for the coop epilogue (~9.7 KB)
struct SMemDot { float red[4]; };
struct SMemRdc { float ps[4][128]; };
struct SMemCmb { float logit[N * N]; float attn[N * N]; float wes[N * N];
                 float xs[128]; int cnt[NREL * N]; };
union SMemU { SMemDot d; SMemRdc r; SMemCmb c; };

// ---- D3 (cooperative, latency-bound work only):
//      B: logits(100) | em_part->em reduce(800) | X-copy(10)   — 910 tasks
//      C: combine + 2nd-layer matvec (352 tasks, kb=128, redundant softmax/block)
//      D: dout left half (40 tasks) ----
__global__ __launch_bounds__(NTHR, 8)
void epi(const float* __restrict__ X, const float* __restrict__ bias,
         const float* __restrict__ root_w, const float* __restrict__ rel_w,
         const float* __restrict__ rel_b, const int* __restrict__ speaker,
         float* __restrict__ ws, float* __restrict__ dout) {
    cg::grid_group grid = cg::this_grid();
    __shared__ SMemU sm;
    int tid  = threadIdx.x;
    int bid  = blockIdx.x;
    int nblk = gridDim.x;

    float* q       = ws + OFF_Q;
    float* kbuf    = ws + OFF_K;
    float* rootacc = ws + OFF_ROOT;
    float* x2acc   = ws + OFF_X2ACC;
    float* aggrel  = ws + OFF_AGGREL;
    float* em      = ws + OFF_EM;
    float* logitsg = ws + OFF_LOGITS;
    float* em_part = ws + OFF_EMPART;

    // ================= phase B =================
    for (int t = bid; t < 910; t += nblk) {
        if (t < 100) {
            int i = t / 10, j = t % 10;
            f32x4 qa = *reinterpret_cast<const f32x4*>(q    + i * D + tid * 4);
            f32x4 ka = *reinterpret_cast<const f32x4*>(kbuf + j * D + tid * 4);
            float part = qa.x * ka.x + qa.y * ka.y + qa.z * ka.z + qa.w * ka.w;
            for (int off = 32; off; off >>= 1) part += __shfl_down(part, off);
            if ((tid & 63) == 0) sm.d.red[tid >> 6] = part;
            __syncthreads();
            if (tid == 0)
                logitsg[t] = (sm.d.red[0] + sm.d.red[1] + sm.d.red[2] + sm.d.red[3])
                             * (1.0f / 32.0f);      // 1/sqrt(1024)
            __syncthreads();
        } else if (t < 900) {
            int rt = t - 100;
            int e = rt >> 3, jt = rt & 7;
            int col = tid & 127, h = tid >> 7;      // 2 by-halves x 128 cols
            int jbase = jt * 128;
            float s = 0.f;
#pragma unroll
            for (int i2 = 0; i2 < KCH / 2; ++i2) {
                int by = h * (KCH / 2) + i2;
                s += em_part[((size_t)(by * (N * N) + e)) * D + jbase + col];
            }
            sm.r.ps[h][col] = s;
            __syncthreads();
            if (tid < 128)
                em[(size_t)e * D + jbase + tid] = sm.r.ps[0][tid] + sm.r.ps[1][tid];
            __syncthreads();
        } else {
            int r = t - 900;                // dout right half: X copy
            f32x4 v = *reinterpret_cast<const f32x4*>(X + r * D + tid * 4);
            *reinterpret_cast<f32x4*>(dout + r * 2 * D + D + tid * 4) = v;
        }
    }
    __threadfence();
    grid.sync();

    // ================= phase C (352 tasks) =================
    for (int t = bid; t < 352; t += nblk) {
        int r    = t >> 5;                  // 0..10 (10 = agg row)
        int rem  = t & 31;
        int cq   = rem & 3, kseg = rem >> 2;
        int kb   = kseg * 128;
        int c    = cq * 256 + tid;
        if (tid < 100) sm.c.logit[tid] = logitsg[tid];
        for (int i2 = tid; i2 < NREL * N; i2 += 256) sm.c.cnt[i2] = 0;
        __syncthreads();
        if (tid < N) {                      // row softmax (redundant per block, cheap)
            float m = -1e30f;
            for (int j = 0; j < N; ++j) m = fmaxf(m, sm.c.logit[tid * N + j]);
            float s = 0.f, ev[N];
            for (int j = 0; j < N; ++j) { ev[j] = expf(sm.c.logit[tid * N + j] - m); s += ev[j]; }
            for (int j = 0; j < N; ++j) sm.c.attn[tid * N + j] = ev[j] / s;
        }
        __syncthreads();
        int et = 0;
        if (tid < 100) {
            int src = tid / N, dst = tid % N;
            et = 2 * (speaker[src] * N + speaker[dst]) + (src >= dst ? 1 : 0);
            atomicAdd(&sm.c.cnt[et * N + dst], 1);
        }
        __syncthreads();
        if (tid < 100) sm.c.wes[tid] = sm.c.attn[tid] / (float)sm.c.cnt[et * N + (tid % N)];
        __syncthreads();
        if (tid < 128) {                    // stage xs = out[r][kb..kb+128)
            int j = kb + tid;
            float v;
            if (r < N) {
                v = rootacc[r * D + j] + bias[j];
#pragma unroll
                for (int src = 0; src < N; ++src)
                    v += sm.c.wes[src * N + r] * em[(size_t)(src * N + r) * D + j];
            } else {                        // agg row = sum_dst out[dst]
                v = (float)N * bias[j];
#pragma unroll
                for (int rr = 0; rr < N; ++rr) v += rootacc[rr * D + j];
                for (int e = 0; e < N * N; ++e) v += sm.c.wes[e] * em[(size_t)e * D + j];
            }
            sm.c.xs[tid] = v;
        }
        __syncthreads();
        const float* W = (r < N) ? root_w : rel_w;
        float*       y = (r < N) ? x2acc + r * D : aggrel;
        const float* Wp = W + (size_t)kb * D + c;
        float acc = 0.f;
#pragma unroll 8
        for (int k = 0; k < 128; ++k) acc += sm.c.xs[k] * Wp[(size_t)k * D];
        atomicAdd(&y[c], acc);
        __syncthreads();                    // protect sm before next task
    }
    __threadfence();
    grid.sync();

    // ================= phase D: dout left half =================
    for (int t = bid; t < 40; t += nblk) {
        int r = t >> 2, cq = t & 3;
        int c = cq * 256 + tid;
        dout[r * 2 * D + c] = x2acc[r * D + c] + aggrel[c] + rel_b[c];
    }
}

// ================== fallback epilogue (R12-exact, known-good) ==================
__global__ void attn_reduce(const float* __restrict__ q, const float* __restrict__ k,
                            const int* __restrict__ speaker,
                            const float* __restrict__ em_part,
                            float* __restrict__ w_e, float* __restrict__ em) {
    int bx  = blockIdx.x;
    int tid = threadIdx.x;
    if (bx < 800) {
        __shared__ float ps[4][128];
        int e = bx >> 3, jt = bx & 7;
        int col = tid & 127, h = tid >> 7;
        int jbase = jt * 128;
        float s = 0.f;
#pragma unroll
        for (int i = 0; i < 8; ++i) {
            int by = h * 8 + i;
            s += em_part[((size_t)(by * (N * N) + e)) * D + jbase + col];
        }
        ps[h][col] = s;
        __syncthreads();
        if (tid < 128)
            em[(size_t)e * D + jbase + tid] = ps[0][tid] + ps[1][tid] + ps[2][tid] + ps[3][tid];
        return;
    }
    __shared__ float logits[N * N];
    __shared__ float attn[N * N];
    __shared__ int   cnt[NREL * N];
    int wave = tid >> 6, lane = tid & 63;
    for (int p = wave; p < N * N; p += 8) {
        int i = p / N, j = p % N;
        const f32x4* qp = reinterpret_cast<const f32x4*>(q + i * D);
        const f32x4* kp = reinterpret_cast<const f32x4*>(k + j * D);
        float acc = 0.f;
#pragma unroll
        for (int it = 0; it < 4; ++it) {
            f32x4 qa = qp[lane + it * 64];
            f32x4 ka = kp[lane + it * 64];
            acc += qa.x * ka.x + qa.y * ka.y + qa.z * ka.z + qa.w * ka.w;
        }
        for (int off = 32; off; off >>= 1) acc += __shfl_down(acc, off);
        if (lane == 0) logits[p] = acc * (1.0f / 32.0f);
    }
    __syncthreads();
    if (tid < N) {
        float m = -1e30f;
        for (int j = 0; j < N; ++j) m = fmaxf(m, logits[tid * N + j]);
        float s = 0.f, e[N];
        for (int j = 0; j < N; ++j) { e[j] = expf(logits[tid * N + j] - m); s += e[j]; }
        for (int j = 0; j < N; ++j) attn[tid * N + j] = e[j] / s;
    }
    for (int i = tid; i < NREL * N; i += 512) cnt[i] = 0;
    __syncthreads();
    int et = 0;
    if (tid < N * N) {
        int src = tid / N, dst = tid % N;
        et = 2 * (speaker[src] * N + speaker[dst]) + (src >= dst ? 1 : 0);
        atomicAdd(&cnt[et * N + dst], 1);
    }
    __syncthreads();
    if (tid < N * N) w_e[tid] = attn[tid] / (float)cnt[et * N + (tid % N)];
}

__global__ void combine_final(const float* __restrict__ em, const float* __restrict__ w_e,
                              const float* __restrict__ rootacc, const float* __restrict__ bias,
                              const float* __restrict__ root_w, const float* __restrict__ rel_w,
                              float* __restrict__ x2acc, float* __restrict__ aggrel) {
    __shared__ float wes[N * N];
    __shared__ float xs[128];
    int r   = blockIdx.x;
    int tid = threadIdx.x;
    int c   = blockIdx.y * 256 + tid;
    int kb  = blockIdx.z * 128;
    if (tid < N * N) wes[tid] = w_e[tid];
    __syncthreads();
    if (tid < 128) {
        int j = kb + tid;
        float v;
        if (r < N) {
            v = rootacc[r * D + j] + bias[j];
#pragma unroll
            for (int src = 0; src < N; ++src) {
                int e = src * N + r;
                v += wes[e] * em[(size_t)e * D + j];
            }
        } else {
            v = (float)N * bias[j];
#pragma unroll
            for (int rr = 0; rr < N; ++rr) v += rootacc[rr * D + j];
            for (int e = 0; e < N * N; ++e) v += wes[e] * em[(size_t)e * D + j];
        }
        xs[tid] = v;
    }
    __syncthreads();
    const float* W = (r < N) ? root_w : rel_w;
    float*       y = (r < N) ? x2acc + r * D : aggrel;
    const float* Wp = W + (size_t)kb * D + c;
    float acc = 0.f;
#pragma unroll 8
    for (int k = 0; k < 128; ++k) acc += xs[k] * Wp[(size_t)k * D];
    atomicAdd(&y[c], acc);
}

__global__ void final_concat(const float* __restrict__ x2acc, const float* __restrict__ aggrel,
                             const float* __restrict__ rel_b, const float* __restrict__ X,
                             float* __restrict__ dout) {
    int r = blockIdx.x, c = blockIdx.y * 256 + threadIdx.x;
    if (c < D) dout[r * 2 * D + c] = x2acc[r * D + c] + aggrel[c] + rel_b[c];
    else       dout[r * 2 * D + c] = X[r * D + (c - D)];
}

extern "C" void kernel_launch(void* const* d_in, const int* in_sizes, int n_in,
                              void* d_out, int out_size, void* d_ws, size_t ws_size,
                              hipStream_t stream) {
    const float* X          = (const float*)d_in[0];
    const int*   speaker    = (const int*)  d_in[1];
    const float* Wq         = (const float*)d_in[2];
    const float* Wk         = (const float*)d_in[3];
    const float* Wrel       = (const float*)d_in[4];
    const float* Wroot      = (const float*)d_in[5];
    const float* bias       = (const float*)d_in[6];
    const float* rel_w      = (const float*)d_in[7];   // gcn_rel_w
    const float* rel_b      = (const float*)d_in[8];   // gcn_rel_b
    const float* root_w     = (const float*)d_in[9];   // gcn_root_w
    float* ws   = (float*)d_ws;
    float* dout = (float*)d_out;

    float* q       = ws + OFF_Q;
    float* kbuf    = ws + OFF_K;
    float* rootacc = ws + OFF_ROOT;
    float* x2acc   = ws + OFF_X2ACC;
    float* aggrel  = ws + OFF_AGGREL;
    float* em      = ws + OFF_EM;
    float* w_e     = ws + OFF_WE;
    int*   nitems  = (int*)(ws + OFF_NITEMS);
    int*   items   = (int*)(ws + OFF_ITEMS);
    float* em_part = ws + OFF_EMPART;

    dim3 blk(NTHR);
    // D1: groups + accumulator zeroing
    build_zero<<<dim3(42), blk, 0, stream>>>(speaker, nitems, items, ws);

    // D2: gather + q/k/root matvecs at FULL occupancy (normal dispatch, R12-exact)
    big_fused<<<dim3(103, KCH), blk, 0, stream>>>(X, Wrel, nitems, items, Wq, Wk, Wroot,
                                                  q, kbuf, rootacc, em_part);

    // D3: post-gather chain in one cooperative kernel, grid sized by occupancy query
    int bpc = 0;
    hipError_t qerr = hipOccupancyMaxActiveBlocksPerMultiprocessor(
        &bpc, (const void*)epi, NTHR, 0);
    int nblk = (qerr == hipSuccess) ? bpc * 256 : 0;
    if (nblk > 1024) nblk = 1024;

    hipError_t cerr = hipErrorUnknown;
    if (nblk >= 512) {
        void* args[] = { (void*)&X, (void*)&bias, (void*)&root_w, (void*)&rel_w,
                         (void*)&rel_b, (void*)&speaker, (void*)&ws, (void*)&dout };
        cerr = hipLaunchCooperativeKernel((void*)epi, dim3(nblk), blk, args, 0, stream);
    }
    if (cerr != hipSuccess) {
        // R12-exact fallback epilogue (105 µs known-good total)
        attn_reduce<<<dim3(801), dim3(512), 0, stream>>>(q, kbuf, speaker, em_part, w_e, em);
        combine_final<<<dim3(N + 1, 4, 8), blk, 0, stream>>>(em, w_e, rootacc, bias,
                                                             root_w, rel_w, x2acc, aggrel);
        final_concat<<<dim3(N, 8), blk, 0, stream>>>(x2acc, aggrel, rel_b, X, dout);
    }
}

// Round 17
// 104.876 us; speedup vs baseline: 5.1185x; 5.1185x over previous
//
#include <hip/hip_runtime.h>

#define N 10
#define D 1024
#define NREL 200
#define KCH 32            // k-slices in the gather (each KLEN rows)
#define KLEN 32           // D / KCH
#define MAXG 8            // max edges per gather group (register-blocked)

typedef float f32x4 __attribute__((ext_vector_type(4)));

// ---------------- workspace layout (float offsets) ----------------
// zeroed each call (build_zero blocks 1..41): [q | k | root | x2acc | aggrel]
#define OFF_Q       0                      // N*D
#define OFF_K       (OFF_Q + N*D)          // N*D
#define OFF_ROOT    (OFF_K + N*D)          // N*D
#define OFF_X2ACC   (OFF_ROOT + N*D)       // N*D
#define OFF_AGGREL  (OFF_X2ACC + N*D)      // D
#define ZERO_FLOATS (OFF_AGGREL + D)       // 41984 = 41 * 1024
#define OFF_EM      ZERO_FLOATS            // N*N*D   (fully overwritten by reduce part)
#define OFF_WE      (OFF_EM + N*N*D)       // 100 (pad 128)
#define OFF_NITEMS  (OFF_WE + 128)         // 1 int (pad 16)
#define OFF_ITEMS   (OFF_NITEMS + 16)      // 100 items x 10 ints
#define OFF_EMPART  (OFF_ITEMS + 1024)     // KCH*N*N*D floats (13.1 MB, overwritten)

// ---- block 0: build etype groups; blocks 1..41: zero the accumulator region ----
__global__ void build_zero(const int* __restrict__ speaker, int* __restrict__ n_items,
                           int* __restrict__ items, float* __restrict__ wsz) {
    if (blockIdx.x > 0) {
        int base = (blockIdx.x - 1) * 1024 + threadIdx.x * 4;
        f32x4 z = 0.f;
        *reinterpret_cast<f32x4*>(wsz + base) = z;
        return;
    }
    __shared__ int sp[N];
    __shared__ int gcnt[NREL];
    __shared__ int ibase[NREL];
    int tid = threadIdx.x;
    if (tid < N) sp[tid] = speaker[tid];
    __syncthreads();
    if (tid < NREL) {
        int c = 0;
        for (int e = 0; e < N * N; ++e) {
            int src = e / N, dst = e % N;
            int et = 2 * (sp[src] * N + sp[dst]) + (src >= dst ? 1 : 0);
            c += (et == tid);
        }
        gcnt[tid] = c;
    }
    __syncthreads();
    if (tid == 0) {
        int b = 0;
        for (int t = 0; t < NREL; ++t) { ibase[t] = b; b += (gcnt[t] + MAXG - 1) / MAXG; }
        *n_items = b;
    }
    __syncthreads();
    if (tid < NREL && gcnt[tid] > 0) {
        int it = ibase[tid], slot = 0;
        int* rec = items + it * 10;
        for (int e = 0; e < N * N; ++e) {
            int src = e / N, dst = e % N;
            int et = 2 * (sp[src] * N + sp[dst]) + (src >= dst ? 1 : 0);
            if (et != tid) continue;
            if (slot == 0) rec[0] = tid;
            rec[2 + slot] = e;
            if (++slot == MAXG) { rec[1] = MAXG; ++it; rec = items + it * 10; slot = 0; }
        }
        if (slot > 0) { rec[1] = slot; for (int g = slot; g < MAXG; ++g) rec[2 + g] = -1; }
    }
}

// ---- [bx<100] etype-grouped weight-gather -> em_part (plain stores, compiler-
//      scheduled unroll-4); [bx>=100] q/k/root pre-matvecs. Full occupancy. ----
__global__ void big_fused(const float* __restrict__ X, const float* __restrict__ Wrel,
                          const int* __restrict__ n_items, const int* __restrict__ items,
                          const float* __restrict__ Wq, const float* __restrict__ Wk,
                          const float* __restrict__ Wroot,
                          float* __restrict__ q, float* __restrict__ kout,
                          float* __restrict__ rootacc, float* __restrict__ em_part) {
    int bx = blockIdx.x, by = blockIdx.y, tid = threadIdx.x;
    if (bx < 100) {
        if (bx >= *n_items) return;        // block-uniform early exit (before any barrier)
        __shared__ int   meta[10];
        __shared__ float xs[MAXG][KLEN];
        if (tid < 10) meta[tid] = items[bx * 10 + tid];
        __syncthreads();
        int t = meta[0], gsize = meta[1];
        {   // stage x slices (zero-padded for g>=gsize so the unrolled FMAs are inert)
            int g = tid >> 5, k = tid & 31;            // 256 threads == MAXG*KLEN
            int e = meta[2 + g];
            xs[g][k] = (g < gsize) ? X[(e / N) * D + by * KLEN + k] : 0.f;
        }
        __syncthreads();
        int c0 = tid * 4;
        const float* W = Wrel + (size_t)t * D * D + (size_t)by * KLEN * D;
        f32x4 acc[MAXG];
#pragma unroll
        for (int g = 0; g < MAXG; ++g) acc[g] = 0.f;
#pragma unroll 4
        for (int k = 0; k < KLEN; ++k) {
            f32x4 w4 = *reinterpret_cast<const f32x4*>(W + (size_t)k * D + c0);
#pragma unroll
            for (int g = 0; g < MAXG; ++g) acc[g] += xs[g][k] * w4;
        }
        for (int g = 0; g < gsize; ++g) {
            *reinterpret_cast<f32x4*>(
                em_part + ((size_t)(by * (N * N) + meta[2 + g])) * D + c0) = acc[g];
        }
    } else {
        int sel = bx - 100;                 // 0:Wq 1:Wk 2:Wroot
        int kb  = (by & 7) * 128;
        int c   = (by >> 3) * 256 + tid;
        const float* W = (sel == 0) ? Wq : (sel == 1) ? Wk : Wroot;
        float*       Y = (sel == 0) ? q  : (sel == 1) ? kout : rootacc;
        __shared__ float xs2[N][128];
        for (int idx = tid; idx < N * 128; idx += 256) {
            int r = idx >> 7, k = idx & 127;
            xs2[r][k] = X[r * D + kb + k];
        }
        __syncthreads();
        float acc[N];
#pragma unroll
        for (int r = 0; r < N; ++r) acc[r] = 0.f;
#pragma unroll 4
        for (int k = 0; k < 128; ++k) {
            float w = W[(size_t)(kb + k) * D + c];
#pragma unroll
            for (int r = 0; r < N; ++r) acc[r] += xs2[r][k] * w;
        }
#pragma unroll
        for (int r = 0; r < N; ++r) atomicAdd(&Y[r * D + c], acc[r]);
    }
}

// ---- merged dispatch, 512 threads: blocks 0..799 reduce em_part -> em;
//      block 800 computes attn -> w_e. All barriers block-uniform.
__global__ void attn_reduce(const float* __restrict__ q, const float* __restrict__ k,
                            const int* __restrict__ speaker,
                            const float* __restrict__ em_part,
                            float* __restrict__ w_e, float* __restrict__ em) {
    int bx  = blockIdx.x;
    int tid = threadIdx.x;
    if (bx < 800) {
        // em[e][jt*128 + col] = sum_{by<32} em_part[by][e][...]
        __shared__ float ps[4][128];
        int e = bx >> 3, jt = bx & 7;
        int col = tid & 127, h = tid >> 7;      // 4 by-quarters x 128 cols
        int jbase = jt * 128;
        float s = 0.f;
#pragma unroll
        for (int i = 0; i < 8; ++i) {
            int by = h * 8 + i;
            s += em_part[((size_t)(by * (N * N) + e)) * D + jbase + col];
        }
        ps[h][col] = s;
        __syncthreads();
        if (tid < 128)
            em[(size_t)e * D + jbase + tid] = ps[0][tid] + ps[1][tid] + ps[2][tid] + ps[3][tid];
        return;
    }
    // ---- attention block (512 threads = 8 waves) ----
    __shared__ float logits[N * N];
    __shared__ float attn[N * N];
    __shared__ int   cnt[NREL * N];   // 8 KB
    int wave = tid >> 6, lane = tid & 63;

    for (int p = wave; p < N * N; p += 8) {
        int i = p / N, j = p % N;
        const f32x4* qp = reinterpret_cast<const f32x4*>(q + i * D);
        const f32x4* kp = reinterpret_cast<const f32x4*>(k + j * D);
        float acc = 0.f;
#pragma unroll
        for (int it = 0; it < 4; ++it) {
            f32x4 qa = qp[lane + it * 64];
            f32x4 ka = kp[lane + it * 64];
            acc += qa.x * ka.x + qa.y * ka.y + qa.z * ka.z + qa.w * ka.w;
        }
        for (int off = 32; off; off >>= 1) acc += __shfl_down(acc, off);
        if (lane == 0) logits[p] = acc * (1.0f / 32.0f);   // 1/sqrt(1024)
    }
    __syncthreads();

    if (tid < N) {                        // row softmax
        float m = -1e30f;
        for (int j = 0; j < N; ++j) m = fmaxf(m, logits[tid * N + j]);
        float s = 0.f, e[N];
        for (int j = 0; j < N; ++j) { e[j] = expf(logits[tid * N + j] - m); s += e[j]; }
        for (int j = 0; j < N; ++j) attn[tid * N + j] = e[j] / s;
    }
    for (int i = tid; i < NREL * N; i += 512) cnt[i] = 0;
    __syncthreads();          // attn visible + cnt zeroed

    int et = 0;
    if (tid < N * N) {
        int src = tid / N, dst = tid % N;
        et = 2 * (speaker[src] * N + speaker[dst]) + (src >= dst ? 1 : 0);
        atomicAdd(&cnt[et * N + dst], 1);
    }
    __syncthreads();          // counts complete (uniform barrier)

    if (tid < N * N) {
        w_e[tid] = attn[tid] / (float)cnt[et * N + (tid % N)];
    }
}

// ---- combine em*w_e + root + bias on the fly, then second-layer matvec ----
// rows 0..9: x2acc[r] += out[r] @ gcn_root_w ; row 10: aggrel += (sum_r out[r]) @ gcn_rel_w
// grid (11, 4, 8), block 256
__global__ void combine_final(const float* __restrict__ em, const float* __restrict__ w_e,
                              const float* __restrict__ rootacc, const float* __restrict__ bias,
                              const float* __restrict__ root_w, const float* __restrict__ rel_w,
                              float* __restrict__ x2acc, float* __restrict__ aggrel) {
    __shared__ float wes[N * N];
    __shared__ float xs[128];
    int r   = blockIdx.x;
    int tid = threadIdx.x;
    int c   = blockIdx.y * 256 + tid;
    int kb  = blockIdx.z * 128;
    if (tid < N * N) wes[tid] = w_e[tid];
    __syncthreads();
    if (tid < 128) {
        int j = kb + tid;
        float v;
        if (r < N) {
            v = rootacc[r * D + j] + bias[j];
#pragma unroll
            for (int src = 0; src < N; ++src) {
                int e = src * N + r;
                v += wes[e] * em[(size_t)e * D + j];
            }
        } else {
            v = (float)N * bias[j];
#pragma unroll
            for (int rr = 0; rr < N; ++rr) v += rootacc[rr * D + j];
            for (int e = 0; e < N * N; ++e) v += wes[e] * em[(size_t)e * D + j];
        }
        xs[tid] = v;
    }
    __syncthreads();
    const float* W = (r < N) ? root_w : rel_w;
    float*       y = (r < N) ? x2acc + r * D : aggrel;
    const float* Wp = W + (size_t)kb * D + c;
    float acc = 0.f;
#pragma unroll 8
    for (int k = 0; k < 128; ++k) acc += xs[k] * Wp[(size_t)k * D];
    atomicAdd(&y[c], acc);
}

// ---- dout[r][0:1024] = x2acc + aggrel + rel_b ; dout[r][1024:2048] = X[r] ----
// grid (10, 8), block 256
__global__ void final_concat(const float* __restrict__ x2acc, const float* __restrict__ aggrel,
                             const float* __restrict__ rel_b, const float* __restrict__ X,
                             float* __restrict__ dout) {
    int r = blockIdx.x, c = blockIdx.y * 256 + threadIdx.x;
    if (c < D) dout[r * 2 * D + c] = x2acc[r * D + c] + aggrel[c] + rel_b[c];
    else       dout[r * 2 * D + c] = X[r * D + (c - D)];
}

extern "C" void kernel_launch(void* const* d_in, const int* in_sizes, int n_in,
                              void* d_out, int out_size, void* d_ws, size_t ws_size,
                              hipStream_t stream) {
    const float* X          = (const float*)d_in[0];
    const int*   speaker    = (const int*)  d_in[1];
    const float* Wq         = (const float*)d_in[2];
    const float* Wk         = (const float*)d_in[3];
    const float* Wrel       = (const float*)d_in[4];
    const float* Wroot      = (const float*)d_in[5];
    const float* bias       = (const float*)d_in[6];
    const float* rel_w      = (const float*)d_in[7];   // gcn_rel_w
    const float* rel_b      = (const float*)d_in[8];   // gcn_rel_b
    const float* root_w     = (const float*)d_in[9];   // gcn_root_w
    float* ws   = (float*)d_ws;
    float* dout = (float*)d_out;

    float* q       = ws + OFF_Q;
    float* kbuf    = ws + OFF_K;
    float* rootacc = ws + OFF_ROOT;
    float* x2acc   = ws + OFF_X2ACC;
    float* aggrel  = ws + OFF_AGGREL;
    float* em      = ws + OFF_EM;
    float* w_e     = ws + OFF_WE;
    int*   nitems  = (int*)(ws + OFF_NITEMS);
    int*   items   = (int*)(ws + OFF_ITEMS);
    float* em_part = ws + OFF_EMPART;

    dim3 blk(256);
    // groups + accumulator zeroing in one dispatch
    build_zero<<<dim3(42), blk, 0, stream>>>(speaker, nitems, items, ws);

    // gather (dedup'd, ~n_items*4MB, full occupancy — probe-measured ~6 TB/s) +
    // q/k/root matvecs in one dispatch
    big_fused<<<dim3(103, KCH), blk, 0, stream>>>(X, Wrel, nitems, items, Wq, Wk, Wroot,
                                                  q, kbuf, rootacc, em_part);

    // attention (1 block) + em_part reduction (800 blocks) in one dispatch
    attn_reduce<<<dim3(801), dim3(512), 0, stream>>>(q, kbuf, speaker, em_part, w_e, em);

    combine_final<<<dim3(N + 1, 4, 8), blk, 0, stream>>>(em, w_e, rootacc, bias,
                                                         root_w, rel_w, x2acc, aggrel);
    final_concat<<<dim3(N, 8), blk, 0, stream>>>(x2acc, aggrel, rel_b, X, dout);
}